// Round 1
// baseline (238.295 us; speedup 1.0000x reference)
//
#include <hip/hip_runtime.h>
#include <math.h>

#define N_TOK   65536
#define HID     1024
#define NEXP    64
#define EPSF    1e-12f
#define TOKB    128     // tokens per block
#define KC      64      // K chunk
#define XPAD    65      // padded row stride for x_lds (conflict-free)

// ws layout: [0..63] inv column norms of sim, [64..127] thr = sigmoid(gates)
__global__ __launch_bounds__(256) void prep_kernel(const float* __restrict__ sim,
                                                   const float* __restrict__ gates,
                                                   float* __restrict__ ws) {
    __shared__ float partial[4][64];
    int e = threadIdx.x & 63;
    int q = threadIdx.x >> 6;   // 0..3
    float s = 0.f;
    for (int h = q * 256; h < q * 256 + 256; ++h) {
        float v = sim[h * NEXP + e];
        s += v * v;
    }
    partial[q][e] = s;
    __syncthreads();
    if (threadIdx.x < 64) {
        float ss = partial[0][e] + partial[1][e] + partial[2][e] + partial[3][e];
        ws[e] = 1.0f / fmaxf(sqrtf(ss), EPSF);
        ws[64 + e] = 1.0f / (1.0f + expf(-gates[e]));
    }
}

__global__ __launch_bounds__(256) void gate_kernel(const float* __restrict__ x,
                                                   const float* __restrict__ sim,
                                                   const float* __restrict__ prep,
                                                   float* __restrict__ out) {
    __shared__ float x_lds[TOKB][XPAD];
    __shared__ float w_lds[KC][NEXP];
    __shared__ float ss_lds[TOKB];
    __shared__ float invcol[NEXP];
    __shared__ float thr_s[NEXP];

    const int tid = threadIdx.x;
    const int base_t = blockIdx.x * TOKB;

    if (tid < NEXP) { invcol[tid] = prep[tid]; thr_s[tid] = prep[64 + tid]; }
    if (tid < TOKB) ss_lds[tid] = 0.f;

    const int g_e = tid & 7;        // expert group 0..7 -> experts 8*g_e..+7
    const int g_t = tid >> 3;       // token group 0..31 -> tokens 4*g_t..+3
    const int e0 = g_e * 8;
    const int t0 = g_t * 4;

    const int lt = tid >> 4;          // 0..15 (stage: token sub-index)
    const int lk = (tid & 15) * 4;    // 0..60 (stage: k offset)

    float acc[4][8];
#pragma unroll
    for (int j = 0; j < 4; ++j)
#pragma unroll
        for (int i = 0; i < 8; ++i) acc[j][i] = 0.f;

    for (int kc = 0; kc < HID; kc += KC) {
        __syncthreads();
        // stage W chunk (64x64), normalized columns
#pragma unroll
        for (int it = 0; it < 4; ++it) {
            int flat4 = it * 256 + tid;          // 0..1023 float4s
            int k = flat4 >> 4;                  // 0..63
            int e = (flat4 & 15) * 4;            // 0..60
            float4 v = *(const float4*)&sim[(size_t)(kc + k) * NEXP + e];
            v.x *= invcol[e]; v.y *= invcol[e + 1]; v.z *= invcol[e + 2]; v.w *= invcol[e + 3];
            *(float4*)&w_lds[k][e] = v;
        }
        // stage X chunk (128 tokens x 64 k), fuse row sum-of-squares
#pragma unroll
        for (int it = 0; it < 8; ++it) {
            int t = it * 16 + lt;                // 0..127
            float4 v = *(const float4*)&x[(size_t)(base_t + t) * HID + kc + lk];
            x_lds[t][lk + 0] = v.x; x_lds[t][lk + 1] = v.y;
            x_lds[t][lk + 2] = v.z; x_lds[t][lk + 3] = v.w;
            float s4 = v.x * v.x + v.y * v.y + v.z * v.z + v.w * v.w;
            s4 += __shfl_xor(s4, 1, 16);
            s4 += __shfl_xor(s4, 2, 16);
            s4 += __shfl_xor(s4, 4, 16);
            s4 += __shfl_xor(s4, 8, 16);
            if ((tid & 15) == 0) ss_lds[t] += s4;
        }
        __syncthreads();
        // inner product accumulate: 32 FMA per k per thread
#pragma unroll 8
        for (int k = 0; k < KC; ++k) {
            float x0 = x_lds[t0 + 0][k];
            float x1 = x_lds[t0 + 1][k];
            float x2 = x_lds[t0 + 2][k];
            float x3 = x_lds[t0 + 3][k];
            float4 w0 = *(const float4*)&w_lds[k][e0];
            float4 w1 = *(const float4*)&w_lds[k][e0 + 4];
            float wv[8] = { w0.x, w0.y, w0.z, w0.w, w1.x, w1.y, w1.z, w1.w };
#pragma unroll
            for (int i = 0; i < 8; ++i) {
                acc[0][i] += x0 * wv[i];
                acc[1][i] += x1 * wv[i];
                acc[2][i] += x2 * wv[i];
                acc[3][i] += x3 * wv[i];
            }
        }
    }

    const size_t out_pre  = (size_t)N_TOK * NEXP;
    const size_t out_mask = 2 * (size_t)N_TOK * NEXP;

#pragma unroll
    for (int j = 0; j < 4; ++j) {
        int t = t0 + j;
        float inv = 1.0f / fmaxf(sqrtf(ss_lds[t]), EPSF);
        float logit[8], pre[8], gated[8];
        int active[8];
        int myact = 0;
#pragma unroll
        for (int i = 0; i < 8; ++i) {
            logit[i] = acc[j][i] * inv;
            pre[i]   = logit[i] - thr_s[e0 + i];
            gated[i] = fmaxf(pre[i], 0.f);
            active[i] = pre[i] > 0.f;
            myact += active[i];
        }
        int rowact = myact;
        rowact += __shfl_xor(rowact, 1, 8);
        rowact += __shfl_xor(rowact, 2, 8);
        rowact += __shfl_xor(rowact, 4, 8);

        float probs[8], mask[8];
        if (rowact > 0) {
            // masked softmax over active experts (inactive -> exp underflows to 0)
            float m = -INFINITY;
#pragma unroll
            for (int i = 0; i < 8; ++i) m = fmaxf(m, active[i] ? gated[i] : -INFINITY);
            m = fmaxf(m, __shfl_xor(m, 1, 8));
            m = fmaxf(m, __shfl_xor(m, 2, 8));
            m = fmaxf(m, __shfl_xor(m, 4, 8));
            float s = 0.f;
#pragma unroll
            for (int i = 0; i < 8; ++i) {
                float ev = active[i] ? expf(gated[i] - m) : 0.f;
                probs[i] = ev; s += ev;
            }
            s += __shfl_xor(s, 1, 8);
            s += __shfl_xor(s, 2, 8);
            s += __shfl_xor(s, 4, 8);
            float rs = 1.0f / s;
#pragma unroll
            for (int i = 0; i < 8; ++i) {
                probs[i] *= rs;
                mask[i] = active[i] ? 1.f : 0.f;
            }
        } else {
            // top-32 fallback: exact 32nd-largest via radix descent on order keys
            unsigned key[8];
#pragma unroll
            for (int i = 0; i < 8; ++i) {
                unsigned u = __float_as_uint(logit[i]);
                key[i] = (u & 0x80000000u) ? ~u : (u | 0x80000000u);
            }
            unsigned cand = 0u;
            for (int bit = 31; bit >= 0; --bit) {
                unsigned test = cand | (1u << bit);
                int c = 0;
#pragma unroll
                for (int i = 0; i < 8; ++i) c += (key[i] >= test);
                c += __shfl_xor(c, 1, 8);
                c += __shfl_xor(c, 2, 8);
                c += __shfl_xor(c, 4, 8);
                if (c >= 32) cand = test;
            }
            // cand == 32nd largest key; select > cand, fill ties by lowest index
            int cgt = 0;
#pragma unroll
            for (int i = 0; i < 8; ++i) cgt += (key[i] > cand);
            cgt += __shfl_xor(cgt, 1, 8);
            cgt += __shfl_xor(cgt, 2, 8);
            cgt += __shfl_xor(cgt, 4, 8);
            int need_eq = 32 - cgt;

            int eqc = 0;
#pragma unroll
            for (int i = 0; i < 8; ++i) eqc += (key[i] == cand);
            int scan = eqc, tmp;
            tmp = __shfl_up(scan, 1, 8); if (g_e >= 1) scan += tmp;
            tmp = __shfl_up(scan, 2, 8); if (g_e >= 2) scan += tmp;
            tmp = __shfl_up(scan, 4, 8); if (g_e >= 4) scan += tmp;
            int run = scan - eqc;   // ties with smaller global index
#pragma unroll
            for (int i = 0; i < 8; ++i) {
                int sel = (key[i] > cand) || ((key[i] == cand) && (run < need_eq));
                run += (key[i] == cand);
                mask[i]  = sel ? 1.f : 0.f;
                probs[i] = sel ? 0.03125f : 0.f;   // gated==0 on fallback rows -> uniform 1/32
            }
        }

        size_t row = (size_t)(base_t + t) * NEXP + e0;
        *(float4*)&out[row]                = make_float4(probs[0], probs[1], probs[2], probs[3]);
        *(float4*)&out[row + 4]            = make_float4(probs[4], probs[5], probs[6], probs[7]);
        *(float4*)&out[out_pre + row]      = make_float4(pre[0], pre[1], pre[2], pre[3]);
        *(float4*)&out[out_pre + row + 4]  = make_float4(pre[4], pre[5], pre[6], pre[7]);
        *(float4*)&out[out_mask + row]     = make_float4(mask[0], mask[1], mask[2], mask[3]);
        *(float4*)&out[out_mask + row + 4] = make_float4(mask[4], mask[5], mask[6], mask[7]);
    }
}

extern "C" void kernel_launch(void* const* d_in, const int* in_sizes, int n_in,
                              void* d_out, int out_size, void* d_ws, size_t ws_size,
                              hipStream_t stream) {
    (void)in_sizes; (void)n_in; (void)out_size; (void)ws_size;
    const float* x     = (const float*)d_in[0];
    const float* sim   = (const float*)d_in[1];
    const float* gates = (const float*)d_in[2];
    float* out = (float*)d_out;
    float* ws  = (float*)d_ws;

    hipLaunchKernelGGL(prep_kernel, dim3(1), dim3(256), 0, stream, sim, gates, ws);
    hipLaunchKernelGGL(gate_kernel, dim3(N_TOK / TOKB), dim3(256), 0, stream, x, sim, ws, out);
}